// Round 7
// baseline (248.047 us; speedup 1.0000x reference)
//
#include <hip/hip_runtime.h>
#include <hip/hip_bf16.h>

// CausalSelfAttention (B=2, T=2048, D=1024, H=16, hd=64).
// fp32 in, fp32 out storage (bf16-space grading). bf16 MFMA pipeline.
// R20: R19 (in-register P, swapped-operand MFMA) cut attn 80->60.8us and
// shifted the profile to latency-underlap: occupancy 12% (~1 wave/SIMD),
// VALU 40%, new 2.2M LDS bank conflicts from quad-dep V b64 LDS reads.
// R16 taught LDS staging == direct global loads; R19 taught P-in-registers
// wins. So: drop the LDS frame entirely. Block = 1 wave (R13 grid, 2048
// blocks, longest-first = LPT balance), K/V fragments loaded DIRECTLY from
// global (qkv / vt), no __shared__, no barriers, no waitcnt drains. V's
// quad-local k-slots become plain vr+0 / vr+16 loads (conflicts gone by
// construction). Math bit-identical to R19. lb(64,3) caps VGPR at 170
// (spill tripwire: VGPR<=72 + FETCH balloon would mean allocator squeezed).
// GEMM side: R18 2-phase double-buffer (proven). transpose_v natural (R10).

typedef __bf16 bf16;
typedef __bf16 bf16x8 __attribute__((ext_vector_type(8)));
typedef __bf16 bf16x4 __attribute__((ext_vector_type(4)));
typedef float f32x4 __attribute__((ext_vector_type(4)));

__device__ __forceinline__ bf16 f2bf(float f) {
    unsigned u = __builtin_bit_cast(unsigned, f);
    u += 0x7fffu + ((u >> 16) & 1u);          // RNE
    unsigned short h = (unsigned short)(u >> 16);
    return __builtin_bit_cast(bf16, h);
}

// pack two f32 -> u32 of 2 bf16 (truncation, matches R19 exactly)
__device__ __forceinline__ unsigned pack2(float a, float b) {
    unsigned ua = __builtin_bit_cast(unsigned, a);
    unsigned ub = __builtin_bit_cast(unsigned, b);
    return (ua >> 16) | (ub & 0xFFFF0000u);
}

__device__ __forceinline__ bf16x8 ld8f(const float* p) {
    f32x4 a = *(const f32x4*)p;
    f32x4 b = *(const f32x4*)(p + 4);
    bf16x8 r;
#pragma unroll
    for (int i = 0; i < 4; i++) { r[i] = f2bf(a[i]); r[i + 4] = f2bf(b[i]); }
    return r;
}

__device__ __forceinline__ void st_out(bf16* p, float v)  { *p = f2bf(v); }
__device__ __forceinline__ void st_out(float* p, float v) { *p = v; }

// fp32 -> bf16 bulk convert
__global__ __launch_bounds__(256) void cvt_bf16(const float* __restrict__ src,
                                                bf16* __restrict__ dst, int n) {
    int i = (blockIdx.x * 256 + threadIdx.x) * 8;
    if (i < n) *(bf16x8*)&dst[i] = ld8f(&src[i]);
}

// async global->LDS, 16B per lane; LDS dest = uniform base + lane*16
__device__ __forceinline__ void glds16(const bf16* g, bf16* l) {
    __builtin_amdgcn_global_load_lds(
        (const __attribute__((address_space(1))) void*)g,
        (__attribute__((address_space(3))) void*)l, 16, 0, 0);
}

// ---------------------------------------------------------------------------
// C[M,N] = A[., lda, +aoff] @ W[N,K]^T, both bf16. global_load_lds staging,
// XOR chunk swizzle (R11-proven). Tile 128 x BN, BK=32, 4 waves.
// R18: double-buffered 2-phase pipeline (stage next || compute current).
// ---------------------------------------------------------------------------
template <typename TC, int BN>
__global__ __launch_bounds__(256) void gemm_glds(const bf16* __restrict__ A, int lda, int aoff,
                                                 const bf16* __restrict__ W,
                                                 TC* __restrict__ C, int N, int K) {
    constexpr int NI = (BN == 128) ? 4 : 2;
    __shared__ bf16 sA[2][128 * 32];
    __shared__ bf16 sW[2][BN * 32];
    const int bm = blockIdx.x * 128, bn = blockIdx.y * BN;
    const int tid = threadIdx.x;
    const int wave = tid >> 6, lane = tid & 63;
    const int quad = lane >> 4, l16 = lane & 15;
    const int rbase = (BN == 128) ? (wave >> 1) * 64 : wave * 32;
    const int cbase = (BN == 128) ? (wave & 1) * 64 : 0;
    const int r16 = lane >> 2, cl = lane & 3;
    const int gch = cl ^ ((r16 >> 1) & 3);
    const int sl  = (l16 >> 1) & 3;

    auto stage = [&](int bufi, int k0) {
#pragma unroll
        for (int t = 0; t < 2; t++) {
            int row = wave * 32 + t * 16 + r16;
            glds16(&A[(size_t)(bm + row) * lda + aoff + k0 + gch * 8],
                   &sA[bufi][(wave * 32 + t * 16) * 32]);
        }
        if (BN == 128) {
#pragma unroll
            for (int t = 0; t < 2; t++) {
                int row = wave * 32 + t * 16 + r16;
                glds16(&W[(size_t)(bn + row) * K + k0 + gch * 8],
                       &sW[bufi][(wave * 32 + t * 16) * 32]);
            }
        } else {
            int row = wave * 16 + r16;
            glds16(&W[(size_t)(bn + row) * K + k0 + gch * 8], &sW[bufi][(wave * 16) * 32]);
        }
    };

    f32x4 acc[NI][4] = {};

    stage(0, 0);
    asm volatile("s_waitcnt vmcnt(0)" ::: "memory");
    __syncthreads();

    const int nsteps = K >> 5;
    for (int s = 0; s < nsteps; s++) {
        const int buf = s & 1;
        if (s + 1 < nsteps) stage(buf ^ 1, (s + 1) * 32);   // overlap w/ compute

        bf16x8 af[NI], bfr[4];
#pragma unroll
        for (int i = 0; i < NI; i++)
            af[i] = *(bf16x8*)&sA[buf][(rbase + i * 16 + l16) * 32 + (quad ^ sl) * 8];
#pragma unroll
        for (int j = 0; j < 4; j++)
            bfr[j] = *(bf16x8*)&sW[buf][(cbase + j * 16 + l16) * 32 + (quad ^ sl) * 8];
#pragma unroll
        for (int i = 0; i < NI; i++)
#pragma unroll
            for (int j = 0; j < 4; j++)
                acc[i][j] = __builtin_amdgcn_mfma_f32_16x16x32_bf16(
                    af[i], bfr[j], acc[i][j], 0, 0, 0);

        asm volatile("s_waitcnt vmcnt(0)" ::: "memory");
        __syncthreads();
    }

#pragma unroll
    for (int i = 0; i < NI; i++)
#pragma unroll
        for (int j = 0; j < 4; j++)
#pragma unroll
            for (int r = 0; r < 4; r++) {
                int row = bm + rbase + i * 16 + quad * 4 + r;
                int col = bn + cbase + j * 16 + l16;
                st_out(&C[(size_t)row * N + col], acc[i][j][r]);
            }
}

// ---------------------------------------------------------------------------
// vt[bh][d][t] = qkv[b][t][2048 + h*64 + d].  Natural order (R10).
// ---------------------------------------------------------------------------
__global__ __launch_bounds__(256) void transpose_v(const bf16* __restrict__ qkv,
                                                   bf16* __restrict__ vt) {
    __shared__ bf16 s[64][72];
    const int tt = blockIdx.x;
    const int bh = blockIdx.y;
    const int b = bh >> 4, h = bh & 15;
    const int tid = threadIdx.x;

    for (int c = tid; c < 512; c += 256) {
        int t = c >> 3, dc = (c & 7) * 8;
        *(bf16x8*)&s[t][dc] =
            *(const bf16x8*)&qkv[((size_t)(b * 2048 + tt * 64 + t)) * 3072 + 2048 + h * 64 + dc];
    }
    __syncthreads();
    for (int c = tid; c < 512; c += 256) {
        int d = c >> 3, tc = (c & 7) * 8;
        bf16x8 o;
#pragma unroll
        for (int e = 0; e < 8; e++) o[e] = s[tc + e][d];
        *(bf16x8*)&vt[((size_t)bh * 64 + d) * 2048 + tt * 64 + tc] = o;
    }
}

// ---------------------------------------------------------------------------
// Flash causal attention, in-register P, zero LDS, zero barriers.
// One wave per block, 32 q-rows, K/V fragments direct from global.
//   S^T[rt][j] = mfma(kb[j], qa[rt])  -> lane holds P(q=rt*16+l16,
//                                        k=j*16+quad*4+r)
//   p = exp2(S*SC-8), mask, lpart += p     (all lane-local)
//   O^T acc[rt][dt] = mfma(vb[dt][c], pB)  (vb: two 8B loads at vr+0/vr+16,
//                                           quad-local k-slots)
// ---------------------------------------------------------------------------
__global__ __launch_bounds__(64, 3) void attn(bf16* __restrict__ qkv,
                                              const bf16* __restrict__ vt) {
    const int bh = blockIdx.x;
    const int i  = 63 - blockIdx.y;       // longest blocks dispatched first
    const int b = bh >> 4, h = bh & 15;
    const int lane = threadIdx.x;
    const int quad = lane >> 4, l16 = lane & 15;

    bf16* base = qkv + (size_t)b * 2048 * 3072;
    const bf16* vbh = vt + (size_t)bh * 64 * 2048;
    const int qb = i * 32;
    const int kint = i >> 1;
    const float SC = 0.125f * 1.44269504f;

    bf16x8 qa[2][2];
#pragma unroll
    for (int rt = 0; rt < 2; rt++)
#pragma unroll
        for (int c = 0; c < 2; c++)
            qa[rt][c] = *(const bf16x8*)&base[(size_t)(qb + rt * 16 + l16) * 3072 +
                                              h * 64 + c * 32 + quad * 8];

    f32x4 acc[2][4] = {};     // O^T: row d=dt*16+quad*4+r, col q=rt*16+l16
    float lpart[2] = {0.0f, 0.0f};

    for (int kt = 0; kt <= kint; kt++) {
        const bool tail = (kt == kint);

        // K fragments (A-operand): K[k=kt*64+j*16+l16][d=c*32+quad*8+e]
        bf16x8 kb[4][2];
#pragma unroll
        for (int j = 0; j < 4; j++) {
            const bf16* kr = &base[(size_t)(kt * 64 + j * 16 + l16) * 3072 + 1024 + h * 64];
            kb[j][0] = *(const bf16x8*)&kr[quad * 8];
            kb[j][1] = *(const bf16x8*)&kr[32 + quad * 8];
        }

        // V fragments (A-operand of PV), quad-local k-slots:
        // element e: k_local = c*32 + (e>>2)*16 + quad*4 + (e&3)
        bf16x8 vb[4][2];
#pragma unroll
        for (int dt = 0; dt < 4; dt++) {
            const bf16* vr = &vbh[(size_t)(dt * 16 + l16) * 2048 + kt * 64 + quad * 4];
#pragma unroll
            for (int c = 0; c < 2; c++) {
                union { bf16x4 h4[2]; bf16x8 v; } u;
                u.h4[0] = *(const bf16x4*)&vr[c * 32];
                u.h4[1] = *(const bf16x4*)&vr[c * 32 + 16];
                vb[dt][c] = u.v;
            }
        }

        // S^T = K @ Q^T : row k = j*16+quad*4+r, col q = rt*16+l16
        f32x4 S[2][4] = {};
#pragma unroll
        for (int j = 0; j < 4; j++)
#pragma unroll
            for (int rt = 0; rt < 2; rt++) {
                S[rt][j] = __builtin_amdgcn_mfma_f32_16x16x32_bf16(kb[j][0], qa[rt][0], S[rt][j], 0, 0, 0);
                S[rt][j] = __builtin_amdgcn_mfma_f32_16x16x32_bf16(kb[j][1], qa[rt][1], S[rt][j], 0, 0, 0);
            }

        // exp + causal mask + lpart + pack (all lane-local)
        unsigned pk[2][4][2];
#pragma unroll
        for (int rt = 0; rt < 2; rt++) {
            const int qg = qb + rt * 16 + l16;
#pragma unroll
            for (int j = 0; j < 4; j++) {
                float p[4];
#pragma unroll
                for (int r = 0; r < 4; r++) {
                    float pv = exp2f(S[rt][j][r] * SC - 8.0f);
                    if (tail) {
                        int kg = kt * 64 + j * 16 + quad * 4 + r;
                        pv = (kg > qg) ? 0.0f : pv;
                    }
                    p[r] = pv;
                }
                lpart[rt] += (p[0] + p[1]) + (p[2] + p[3]);
                pk[rt][j][0] = pack2(p[0], p[1]);
                pk[rt][j][1] = pack2(p[2], p[3]);
            }
        }

        // PV: O^T += V^T @ P^T.
        // pB element e = P[q=rt*16+l16][k=c*32+(e>>2)*16+quad*4+(e&3)]
#pragma unroll
        for (int rt = 0; rt < 2; rt++)
#pragma unroll
            for (int c = 0; c < 2; c++) {
                union { unsigned u[4]; bf16x8 v; } pb;
                pb.u[0] = pk[rt][2 * c][0];
                pb.u[1] = pk[rt][2 * c][1];
                pb.u[2] = pk[rt][2 * c + 1][0];
                pb.u[3] = pk[rt][2 * c + 1][1];
#pragma unroll
                for (int dt = 0; dt < 4; dt++)
                    acc[rt][dt] = __builtin_amdgcn_mfma_f32_16x16x32_bf16(
                        vb[dt][c], pb.v, acc[rt][dt], 0, 0, 0);
            }
    }

    // epilogue: reduce lpart across the 4 quads (k-slices), scale, store.
#pragma unroll
    for (int rt = 0; rt < 2; rt++) {
        lpart[rt] += __shfl_xor(lpart[rt], 16);
        lpart[rt] += __shfl_xor(lpart[rt], 32);
    }

#pragma unroll
    for (int rt = 0; rt < 2; rt++) {
        float inv = 1.0f / lpart[rt];
        int row = qb + rt * 16 + l16;
#pragma unroll
        for (int dt = 0; dt < 4; dt++) {
            bf16x4 o;
#pragma unroll
            for (int r = 0; r < 4; r++) o[r] = f2bf(acc[rt][dt][r] * inv);
            *(bf16x4*)&base[(size_t)row * 3072 + 2048 + h * 64 + dt * 16 + quad * 4] = o;
        }
    }
}

extern "C" void kernel_launch(void* const* d_in, const int* in_sizes, int n_in,
                              void* d_out, int out_size, void* d_ws, size_t ws_size,
                              hipStream_t stream) {
    (void)out_size; (void)ws_size;
    const float *x = (const float*)d_in[0], *w_qkv = (const float*)d_in[1],
                *w_proj = (const float*)d_in[2];
    for (int i = 0; i < n_in; i++) {
        if (in_sizes[i] == 4194304) x = (const float*)d_in[i];
        else if (in_sizes[i] == 3145728) w_qkv = (const float*)d_in[i];
        else if (in_sizes[i] == 1048576) w_proj = (const float*)d_in[i];
    }

    float* out = (float*)d_out;                    // [4096,1024] fp32
    bf16* xb   = (bf16*)d_out;                     // 8.4MB scratch in d_out
    bf16* qkv  = (bf16*)d_ws;                      // [4096,3072] bf16 (25.2MB)
    bf16* r2   = qkv + (size_t)4096 * 3072;        // 8.4MB: wqb -> vt -> wpb
    bf16* wqb  = r2;
    bf16* vt   = r2;
    bf16* wpb  = r2;

    cvt_bf16<<<dim3(2048), dim3(256), 0, stream>>>(x, xb, 4096 * 1024);
    cvt_bf16<<<dim3(1536), dim3(256), 0, stream>>>(w_qkv, wqb, 3072 * 1024);
    gemm_glds<bf16, 128><<<dim3(32, 24), dim3(256), 0, stream>>>(
        xb, 1024, 0, wqb, qkv, 3072, 1024);
    transpose_v<<<dim3(32, 32), dim3(256), 0, stream>>>(qkv, vt);
    attn<<<dim3(32, 64), dim3(64), 0, stream>>>(qkv, vt);
    cvt_bf16<<<dim3(512), dim3(256), 0, stream>>>(w_proj, wpb, 1024 * 1024);
    gemm_glds<float, 128><<<dim3(32, 8), dim3(256), 0, stream>>>(
        qkv, 3072, 2048, wpb, out, 1024, 1024);
}

// Round 8
// 197.297 us; speedup vs baseline: 1.2572x; 1.2572x over previous
//
#include <hip/hip_runtime.h>
#include <hip/hip_bf16.h>

// CausalSelfAttention (B=2, T=2048, D=1024, H=16, hd=64).
// fp32 in, fp32 out storage (bf16-space grading). bf16 MFMA pipeline.
// R21: R20 (no-LDS direct loads) regressed 60.8->107.7us -> R16's "staging
// doesn't matter" was masked by the old sP round-trip; post-R19 the LDS
// staging is load-bearing. Revert to R19 frame + ONE change: 2-wave blocks.
// Block = q-tiles {2g, 2g+1}: both waves have kint == g (perfect uniformity,
// zero idle iterations). Grid (32,32) = 1024 blocks = 4/CU; slot mapping
// y->g gives every CU the set {31-k, 16+k, 15-k, k} -> all CUs total 66
// iterations exactly; 3-4 independent blocks co-resident during the long
// block's run (R19's tail ran 1 wave/SIMD -> everything summed; this is the
// occupancy-12% fix). R19 math/staging/epilogue byte-identical.
// GEMM side: R18 2-phase double-buffer (proven). transpose_v natural (R10).

typedef __bf16 bf16;
typedef __bf16 bf16x8 __attribute__((ext_vector_type(8)));
typedef __bf16 bf16x4 __attribute__((ext_vector_type(4)));
typedef float f32x4 __attribute__((ext_vector_type(4)));

__device__ __forceinline__ bf16 f2bf(float f) {
    unsigned u = __builtin_bit_cast(unsigned, f);
    u += 0x7fffu + ((u >> 16) & 1u);          // RNE
    unsigned short h = (unsigned short)(u >> 16);
    return __builtin_bit_cast(bf16, h);
}

// pack two f32 -> u32 of 2 bf16 (truncation, matches R19 exactly)
__device__ __forceinline__ unsigned pack2(float a, float b) {
    unsigned ua = __builtin_bit_cast(unsigned, a);
    unsigned ub = __builtin_bit_cast(unsigned, b);
    return (ua >> 16) | (ub & 0xFFFF0000u);
}

__device__ __forceinline__ bf16x8 ld8f(const float* p) {
    f32x4 a = *(const f32x4*)p;
    f32x4 b = *(const f32x4*)(p + 4);
    bf16x8 r;
#pragma unroll
    for (int i = 0; i < 4; i++) { r[i] = f2bf(a[i]); r[i + 4] = f2bf(b[i]); }
    return r;
}

__device__ __forceinline__ void st_out(bf16* p, float v)  { *p = f2bf(v); }
__device__ __forceinline__ void st_out(float* p, float v) { *p = v; }

// fp32 -> bf16 bulk convert
__global__ __launch_bounds__(256) void cvt_bf16(const float* __restrict__ src,
                                                bf16* __restrict__ dst, int n) {
    int i = (blockIdx.x * 256 + threadIdx.x) * 8;
    if (i < n) *(bf16x8*)&dst[i] = ld8f(&src[i]);
}

// async global->LDS, 16B per lane; LDS dest = uniform base + lane*16
__device__ __forceinline__ void glds16(const bf16* g, bf16* l) {
    __builtin_amdgcn_global_load_lds(
        (const __attribute__((address_space(1))) void*)g,
        (__attribute__((address_space(3))) void*)l, 16, 0, 0);
}

// ---------------------------------------------------------------------------
// C[M,N] = A[., lda, +aoff] @ W[N,K]^T, both bf16. global_load_lds staging,
// XOR chunk swizzle (R11-proven). Tile 128 x BN, BK=32, 4 waves.
// R18: double-buffered 2-phase pipeline (stage next || compute current).
// ---------------------------------------------------------------------------
template <typename TC, int BN>
__global__ __launch_bounds__(256) void gemm_glds(const bf16* __restrict__ A, int lda, int aoff,
                                                 const bf16* __restrict__ W,
                                                 TC* __restrict__ C, int N, int K) {
    constexpr int NI = (BN == 128) ? 4 : 2;
    __shared__ bf16 sA[2][128 * 32];
    __shared__ bf16 sW[2][BN * 32];
    const int bm = blockIdx.x * 128, bn = blockIdx.y * BN;
    const int tid = threadIdx.x;
    const int wave = tid >> 6, lane = tid & 63;
    const int quad = lane >> 4, l16 = lane & 15;
    const int rbase = (BN == 128) ? (wave >> 1) * 64 : wave * 32;
    const int cbase = (BN == 128) ? (wave & 1) * 64 : 0;
    const int r16 = lane >> 2, cl = lane & 3;
    const int gch = cl ^ ((r16 >> 1) & 3);
    const int sl  = (l16 >> 1) & 3;

    auto stage = [&](int bufi, int k0) {
#pragma unroll
        for (int t = 0; t < 2; t++) {
            int row = wave * 32 + t * 16 + r16;
            glds16(&A[(size_t)(bm + row) * lda + aoff + k0 + gch * 8],
                   &sA[bufi][(wave * 32 + t * 16) * 32]);
        }
        if (BN == 128) {
#pragma unroll
            for (int t = 0; t < 2; t++) {
                int row = wave * 32 + t * 16 + r16;
                glds16(&W[(size_t)(bn + row) * K + k0 + gch * 8],
                       &sW[bufi][(wave * 32 + t * 16) * 32]);
            }
        } else {
            int row = wave * 16 + r16;
            glds16(&W[(size_t)(bn + row) * K + k0 + gch * 8], &sW[bufi][(wave * 16) * 32]);
        }
    };

    f32x4 acc[NI][4] = {};

    stage(0, 0);
    asm volatile("s_waitcnt vmcnt(0)" ::: "memory");
    __syncthreads();

    const int nsteps = K >> 5;
    for (int s = 0; s < nsteps; s++) {
        const int buf = s & 1;
        if (s + 1 < nsteps) stage(buf ^ 1, (s + 1) * 32);   // overlap w/ compute

        bf16x8 af[NI], bfr[4];
#pragma unroll
        for (int i = 0; i < NI; i++)
            af[i] = *(bf16x8*)&sA[buf][(rbase + i * 16 + l16) * 32 + (quad ^ sl) * 8];
#pragma unroll
        for (int j = 0; j < 4; j++)
            bfr[j] = *(bf16x8*)&sW[buf][(cbase + j * 16 + l16) * 32 + (quad ^ sl) * 8];
#pragma unroll
        for (int i = 0; i < NI; i++)
#pragma unroll
            for (int j = 0; j < 4; j++)
                acc[i][j] = __builtin_amdgcn_mfma_f32_16x16x32_bf16(
                    af[i], bfr[j], acc[i][j], 0, 0, 0);

        asm volatile("s_waitcnt vmcnt(0)" ::: "memory");
        __syncthreads();
    }

#pragma unroll
    for (int i = 0; i < NI; i++)
#pragma unroll
        for (int j = 0; j < 4; j++)
#pragma unroll
            for (int r = 0; r < 4; r++) {
                int row = bm + rbase + i * 16 + quad * 4 + r;
                int col = bn + cbase + j * 16 + l16;
                st_out(&C[(size_t)row * N + col], acc[i][j][r]);
            }
}

// ---------------------------------------------------------------------------
// vt[bh][d][t] = qkv[b][t][2048 + h*64 + d].  Natural order (R10).
// ---------------------------------------------------------------------------
__global__ __launch_bounds__(256) void transpose_v(const bf16* __restrict__ qkv,
                                                   bf16* __restrict__ vt) {
    __shared__ bf16 s[64][72];
    const int tt = blockIdx.x;
    const int bh = blockIdx.y;
    const int b = bh >> 4, h = bh & 15;
    const int tid = threadIdx.x;

    for (int c = tid; c < 512; c += 256) {
        int t = c >> 3, dc = (c & 7) * 8;
        *(bf16x8*)&s[t][dc] =
            *(const bf16x8*)&qkv[((size_t)(b * 2048 + tt * 64 + t)) * 3072 + 2048 + h * 64 + dc];
    }
    __syncthreads();
    for (int c = tid; c < 512; c += 256) {
        int d = c >> 3, tc = (c & 7) * 8;
        bf16x8 o;
#pragma unroll
        for (int e = 0; e < 8; e++) o[e] = s[tc + e][d];
        *(bf16x8*)&vt[((size_t)bh * 64 + d) * 2048 + tt * 64 + tc] = o;
    }
}

// ---------------------------------------------------------------------------
// Flash causal attention, in-register P (swapped-operand MFMA), 2-wave
// blocks. Block = q-tiles {2g, 2g+1}, one per wave; both waves have
// kint == g (uniform trip count, no idle iterations). K/V staged per block
// into LDS via glds16 (double-buffered, XOR chunk swizzle). Per tile:
//   S^T[rt][j] = mfma(kb[j], qa[rt]) -> lane holds P(q=rt*16+l16,
//                                        k=j*16+quad*4+r)
//   p = exp2(S*SC-8), mask, lpart += p   (lane-local)
//   O^T acc[rt][dt] = mfma(vb[dt][c], pB)  (vb: quad-local k-slot b64 reads)
// No sP, no DS writes, no lgkm drains in the body.
// ---------------------------------------------------------------------------
__global__ __launch_bounds__(128, 2) void attn(bf16* __restrict__ qkv,
                                               const bf16* __restrict__ vt) {
    const int bh = blockIdx.x;
    const int y  = blockIdx.y;
    // slot mapping: per-CU g-set {31-k, 16+k, 15-k, k} -> equal 66 iters/CU
    // y in [0,8): 31-y | [8,16): y+8 | [16,24): 31-y | [24,32): y-24
    const int g  = (y & 8) ? ((y & 16) ? (y - 24) : (y + 8)) : (31 - y);
    const int b = bh >> 4, h = bh & 15;
    const int tid  = threadIdx.x;
    const int wave = tid >> 6;            // 0..1
    const int lane = tid & 63;
    const int quad = lane >> 4, l16 = lane & 15;

    __shared__ bf16 sK[2][64 * 64];   // 16 KB (2 bufs)
    __shared__ bf16 sV[2][64 * 64];   // 16 KB

    bf16* base = qkv + (size_t)b * 2048 * 3072;
    const bf16* vbh = vt + (size_t)bh * 64 * 2048;

    const int iq = g * 2 + wave;          // this wave's q-tile (0..63)
    const int qb = iq * 32;
    const int kint = g;                   // == iq>>1 for both waves
    const float SC = 0.125f * 1.44269504f;

    // staging source: lane -> (row within 8-row group, swizzled chunk)
    const int srow = lane >> 3;           // 0..7
    const int schk = (lane & 7) ^ srow;   // inverse-swizzled source chunk

    auto stage = [&](int bufi, int kt) {
#pragma unroll
        for (int u = 0; u < 4; u++) {
            int s = wave * 4 + u;         // 8 parts over 2 waves, 4 each
            glds16(&base[(size_t)(kt * 64 + s * 8 + srow) * 3072 + 1024 + h * 64 + schk * 8],
                   &sK[bufi][s * 512]);
            glds16(&vbh[(size_t)(s * 8 + srow) * 2048 + kt * 64 + schk * 8],
                   &sV[bufi][s * 512]);
        }
    };

    bf16x8 qa[2][2];
#pragma unroll
    for (int rt = 0; rt < 2; rt++)
#pragma unroll
        for (int c = 0; c < 2; c++)
            qa[rt][c] = *(const bf16x8*)&base[(size_t)(qb + rt * 16 + l16) * 3072 +
                                              h * 64 + c * 32 + quad * 8];

    f32x4 acc[2][4] = {};     // O^T: row d=dt*16+quad*4+r, col q=rt*16+l16
    float lpart[2] = {0.0f, 0.0f};
    const int sw = l16 & 7;               // read-side swizzle key (= row&7)

    auto body = [&](int kt, bool tail, int bufi) {
        const bf16* K = sK[bufi];
        const bf16* V = sV[bufi];

        // K fragments (A-operand): K[k=j*16+l16][d=c*32+quad*8+e]
        bf16x8 kb[4][2];
#pragma unroll
        for (int j = 0; j < 4; j++)
#pragma unroll
            for (int c = 0; c < 2; c++)
                kb[j][c] = *(const bf16x8*)&K[(j * 16 + l16) * 64 + ((c * 4 + quad) ^ sw) * 8];

        // V fragments (A-operand of PV), quad-local k-slots:
        // element e: k_local = (2c+(e>>2))*16 + quad*4 + (e&3)
        bf16x8 vb[4][2];
#pragma unroll
        for (int dt = 0; dt < 4; dt++)
#pragma unroll
            for (int c = 0; c < 2; c++) {
                const bf16* vr = &V[(dt * 16 + l16) * 64];
                union { bf16x4 h4[2]; bf16x8 v; } u;
                u.h4[0] = *(const bf16x4*)&vr[((4 * c +     (quad >> 1)) ^ sw) * 8 + (quad & 1) * 4];
                u.h4[1] = *(const bf16x4*)&vr[((4 * c + 2 + (quad >> 1)) ^ sw) * 8 + (quad & 1) * 4];
                vb[dt][c] = u.v;
            }

        // S^T = K @ Q^T : row k = j*16+quad*4+r, col q = rt*16+l16
        f32x4 S[2][4] = {};
#pragma unroll
        for (int j = 0; j < 4; j++)
#pragma unroll
            for (int rt = 0; rt < 2; rt++) {
                S[rt][j] = __builtin_amdgcn_mfma_f32_16x16x32_bf16(kb[j][0], qa[rt][0], S[rt][j], 0, 0, 0);
                S[rt][j] = __builtin_amdgcn_mfma_f32_16x16x32_bf16(kb[j][1], qa[rt][1], S[rt][j], 0, 0, 0);
            }

        // exp + causal mask + lpart + pack (all lane-local)
        unsigned pk[2][4][2];
#pragma unroll
        for (int rt = 0; rt < 2; rt++) {
            const int qg = qb + rt * 16 + l16;
#pragma unroll
            for (int j = 0; j < 4; j++) {
                float p[4];
#pragma unroll
                for (int r = 0; r < 4; r++) {
                    float pv = exp2f(S[rt][j][r] * SC - 8.0f);
                    if (tail) {
                        int kg = kt * 64 + j * 16 + quad * 4 + r;
                        pv = (kg > qg) ? 0.0f : pv;
                    }
                    p[r] = pv;
                }
                lpart[rt] += (p[0] + p[1]) + (p[2] + p[3]);
                pk[rt][j][0] = pack2(p[0], p[1]);
                pk[rt][j][1] = pack2(p[2], p[3]);
            }
        }

        // PV: O^T += V^T @ P^T. pB element e = P[q=rt*16+l16][k=(2c+(e>>2))*16+quad*4+(e&3)]
#pragma unroll
        for (int rt = 0; rt < 2; rt++)
#pragma unroll
            for (int c = 0; c < 2; c++) {
                union { unsigned u[4]; bf16x8 v; } pb;
                pb.u[0] = pk[rt][2 * c][0];
                pb.u[1] = pk[rt][2 * c][1];
                pb.u[2] = pk[rt][2 * c + 1][0];
                pb.u[3] = pk[rt][2 * c + 1][1];
#pragma unroll
                for (int dt = 0; dt < 4; dt++)
                    acc[rt][dt] = __builtin_amdgcn_mfma_f32_16x16x32_bf16(
                        vb[dt][c], pb.v, acc[rt][dt], 0, 0, 0);
            }
    };

    // double-buffered kt loop; uniform trip count for both waves
    stage(0, 0);
    asm volatile("s_waitcnt vmcnt(0)" ::: "memory");
    __syncthreads();
    int buf = 0;
    for (int kt = 0; kt <= kint; kt++) {
        if (kt + 1 <= kint) stage(buf ^ 1, kt + 1);
        body(kt, kt == kint, buf);
        asm volatile("s_waitcnt vmcnt(0)" ::: "memory");
        __syncthreads();
        buf ^= 1;
    }

    // epilogue: reduce lpart across the 4 quads (k-slices), scale, store.
#pragma unroll
    for (int rt = 0; rt < 2; rt++) {
        lpart[rt] += __shfl_xor(lpart[rt], 16);
        lpart[rt] += __shfl_xor(lpart[rt], 32);
    }

#pragma unroll
    for (int rt = 0; rt < 2; rt++) {
        float inv = 1.0f / lpart[rt];
        int row = qb + rt * 16 + l16;
#pragma unroll
        for (int dt = 0; dt < 4; dt++) {
            bf16x4 o;
#pragma unroll
            for (int r = 0; r < 4; r++) o[r] = f2bf(acc[rt][dt][r] * inv);
            *(bf16x4*)&base[(size_t)row * 3072 + 2048 + h * 64 + dt * 16 + quad * 4] = o;
        }
    }
}

extern "C" void kernel_launch(void* const* d_in, const int* in_sizes, int n_in,
                              void* d_out, int out_size, void* d_ws, size_t ws_size,
                              hipStream_t stream) {
    (void)out_size; (void)ws_size;
    const float *x = (const float*)d_in[0], *w_qkv = (const float*)d_in[1],
                *w_proj = (const float*)d_in[2];
    for (int i = 0; i < n_in; i++) {
        if (in_sizes[i] == 4194304) x = (const float*)d_in[i];
        else if (in_sizes[i] == 3145728) w_qkv = (const float*)d_in[i];
        else if (in_sizes[i] == 1048576) w_proj = (const float*)d_in[i];
    }

    float* out = (float*)d_out;                    // [4096,1024] fp32
    bf16* xb   = (bf16*)d_out;                     // 8.4MB scratch in d_out
    bf16* qkv  = (bf16*)d_ws;                      // [4096,3072] bf16 (25.2MB)
    bf16* r2   = qkv + (size_t)4096 * 3072;        // 8.4MB: wqb -> vt -> wpb
    bf16* wqb  = r2;
    bf16* vt   = r2;
    bf16* wpb  = r2;

    cvt_bf16<<<dim3(2048), dim3(256), 0, stream>>>(x, xb, 4096 * 1024);
    cvt_bf16<<<dim3(1536), dim3(256), 0, stream>>>(w_qkv, wqb, 3072 * 1024);
    gemm_glds<bf16, 128><<<dim3(32, 24), dim3(256), 0, stream>>>(
        xb, 1024, 0, wqb, qkv, 3072, 1024);
    transpose_v<<<dim3(32, 32), dim3(256), 0, stream>>>(qkv, vt);
    attn<<<dim3(32, 32), dim3(128), 0, stream>>>(qkv, vt);
    cvt_bf16<<<dim3(512), dim3(256), 0, stream>>>(w_proj, wpb, 1024 * 1024);
    gemm_glds<float, 128><<<dim3(32, 8), dim3(256), 0, stream>>>(
        qkv, 3072, 2048, wpb, out, 1024, 1024);
}